// Round 11
// baseline (470.149 us; speedup 1.0000x reference)
//
#include <hip/hip_runtime.h>
#include <hip/hip_cooperative_groups.h>
#include <cstdint>
#include <cstddef>

namespace cg = cooperative_groups;

// B=8, C=256, N=1024, T=60
// seq [B][C][N][T] fp32 (503 MB), out [B][T][T] fp32
//
// R11: kA FROZEN (~89us ~roofline, R8 probe). Entire tail fused into ONE
// cooperative kernel KT (992 blocks x 256 thr, 3 grid.sync()): phase1 = K1
// (f2 reduce + g1 partial GEMM), phase2 = kD (direct f2 reads, no 61KB slab),
// phase3 = kE, phase4 = kG (per-block redundant BN stats). 2 launches total.
//
// ws layout (float offsets):
//   f1p : [8 cg][B][60][1024]                 -> 3,932,160  @ 0
//   f2p : [B][C][16 chunks][60]               -> 1,966,080  @ 3,932,160
//   f2  : [B][C][60]                          ->   122,880  @ 5,898,240
//   g1p : [4 ks][B][60][C] partials over n    ->   491,520  @ 6,021,120
//   logits: [B][60][60]                       ->    28,800  @ 6,512,640
//   l2  : [B][60][60]                         ->    28,800  @ 6,541,440

#define CSTRIDE 61440  // 1024*60 floats per c-plane

typedef float vfloat4 __attribute__((ext_vector_type(4)));

// quad-lane (xor1 + xor2) sum via DPP quad_perm — VALU only, no LDS pipe.
__device__ __forceinline__ float quad_reduce(float x) {
    int y1 = __builtin_amdgcn_update_dpp(0, __float_as_int(x), 0xB1, 0xF, 0xF, true);
    float s1 = x + __int_as_float(y1);
    int y2 = __builtin_amdgcn_update_dpp(0, __float_as_int(s1), 0x4E, 0xF, 0xF, true);
    return s1 + __int_as_float(y2);
}

// ---------------------------------------------------------------------------
// Kernel A (FROZEN from R7; ~89us, ~roofline): 4-deep NT pipeline; DPP f2
// reduce; LDS buffer; cross-wave reduce + flush to f2p [B][C][16][60].
// ---------------------------------------------------------------------------
__global__ __launch_bounds__(256) void kA(const float* __restrict__ seq,
                                          const float* __restrict__ w1,
                                          const float* __restrict__ w2,
                                          float* __restrict__ f1p,
                                          float* __restrict__ f2p) {
    const int blk  = blockIdx.x;            // 1024
    const int b    = blk >> 7;              // 0..7
    const int cg_  = (blk >> 4) & 7;        // 0..7
    const int nc   = blk & 15;              // 0..15
    const int tid  = threadIdx.x;
    const int wv   = tid >> 6;              // 0..3
    const int lane = tid & 63;
    const int q    = lane & 3;              // n-sub
    const int r    = lane >> 2;             // t-quad; r==15 inactive
    const bool act = (r < 15);
    const int base_n = (nc << 6) + (wv << 4);
    const int c0   = cg_ << 5;

    __shared__ float lf2[7680];             // [cc 32][wv 4][60]

    float w2v[4];
    #pragma unroll
    for (int j = 0; j < 4; ++j) w2v[j] = w2[base_n + 4 * j + q];

    const size_t planeOff = (size_t)(b * 256 + c0) * CSTRIDE + (size_t)((base_n + q) * 60 + 4 * r);
    const float* p0 = seq + planeOff;
    const float* p1 = p0 + (size_t)CSTRIDE;
    const float* p2 = p0 + 2 * (size_t)CSTRIDE;
    const float* p3 = p0 + 3 * (size_t)CSTRIDE;

    vfloat4 P0[4], P1[4], P2[4], P3[4];
    #pragma unroll
    for (int j = 0; j < 4; ++j) {
        P0[j] = (vfloat4)(0.f);
        P1[j] = P0[j]; P2[j] = P0[j]; P3[j] = P0[j];
    }
    if (act) {
        #pragma unroll
        for (int j = 0; j < 4; ++j) P0[j] = __builtin_nontemporal_load((const vfloat4*)(p0 + j * 240));
        #pragma unroll
        for (int j = 0; j < 4; ++j) P1[j] = __builtin_nontemporal_load((const vfloat4*)(p1 + j * 240));
        #pragma unroll
        for (int j = 0; j < 4; ++j) P2[j] = __builtin_nontemporal_load((const vfloat4*)(p2 + j * 240));
        #pragma unroll
        for (int j = 0; j < 4; ++j) P3[j] = __builtin_nontemporal_load((const vfloat4*)(p3 + j * 240));
    }
    p0 += 4 * (size_t)CSTRIDE;
    p1 += 4 * (size_t)CSTRIDE;
    p2 += 4 * (size_t)CSTRIDE;
    p3 += 4 * (size_t)CSTRIDE;

    vfloat4 acc[4];
    #pragma unroll
    for (int j = 0; j < 4; ++j) acc[j] = (vfloat4)(0.f);

#define KA_STEP(P, S, PP)                                                               \
    {                                                                                   \
        const int cc = (ii << 2) + (S);                                                 \
        const float wc = w1[c0 + cc];                                                   \
        _Pragma("unroll")                                                               \
        for (int j = 0; j < 4; ++j) acc[j] += wc * P[j];                                \
        vfloat4 f2v = w2v[0]*P[0] + w2v[1]*P[1] + w2v[2]*P[2] + w2v[3]*P[3];            \
        if (pref) {                                                                     \
            _Pragma("unroll")                                                           \
            for (int j = 0; j < 4; ++j)                                                 \
                P[j] = __builtin_nontemporal_load((const vfloat4*)((PP) + j * 240));    \
        }                                                                               \
        f2v.x = quad_reduce(f2v.x);                                                     \
        f2v.y = quad_reduce(f2v.y);                                                     \
        f2v.z = quad_reduce(f2v.z);                                                     \
        f2v.w = quad_reduce(f2v.w);                                                     \
        if (act && q == 0) {                                                            \
            *(vfloat4*)(&lf2[(cc * 4 + wv) * 60 + 4 * r]) = f2v;                        \
        }                                                                               \
    }

    for (int ii = 0; ii < 8; ++ii) {
        const bool pref = act && (ii < 7);
        KA_STEP(P0, 0, p0)
        KA_STEP(P1, 1, p1)
        KA_STEP(P2, 2, p2)
        KA_STEP(P3, 3, p3)
        p0 += 4 * (size_t)CSTRIDE;
        p1 += 4 * (size_t)CSTRIDE;
        p2 += 4 * (size_t)CSTRIDE;
        p3 += 4 * (size_t)CSTRIDE;
    }
#undef KA_STEP

    if (act) {
        float* dst = f1p + ((size_t)((cg_ * 8 + b) * 60 + 4 * r)) * 1024 + base_n + q;
        #pragma unroll
        for (int j = 0; j < 4; ++j) {
            dst[0 * 1024 + 4 * j] = acc[j].x;
            dst[1 * 1024 + 4 * j] = acc[j].y;
            dst[2 * 1024 + 4 * j] = acc[j].z;
            dst[3 * 1024 + 4 * j] = acc[j].w;
        }
    }

    __syncthreads();
    #pragma unroll
    for (int k = 0; k < 2; ++k) {
        const int id4 = tid + k * 256;
        if (id4 < 480) {
            const int cc = id4 / 15;
            const int p  = id4 - cc * 15;
            vfloat4 s = (vfloat4)(0.f);
            #pragma unroll
            for (int w_ = 0; w_ < 4; ++w_)
                s += *(const vfloat4*)(&lf2[(cc * 4 + w_) * 60 + 4 * p]);
            *(vfloat4*)(f2p + ((size_t)(b * 256 + c0 + cc) * 16 + nc) * 60 + 4 * p) = s;
        }
    }
}

// ---------------------------------------------------------------------------
// KT: cooperative fused tail. 992 blocks x 256 threads, 3 grid syncs.
//  P1: blocks [0,512) f2 = sum16 f2p chunks; [512,992) g1p partial GEMM.
//  P2: blocks [0,480) logits = sigmoid(g1·f2 + bmat)  (direct f2 reads).
//  P3: blocks [0,480) l2 = v @ logits (logits[b] staged in LDS).
//  P4: blocks [0,480) per-block BN stats + BN + mask + softmax -> out.
// LDS union: 3600 floats (14.4 KB) -> >=4 blocks/CU with launch_bounds(256,4).
// ---------------------------------------------------------------------------
__global__ __launch_bounds__(256, 4) void KT(const float* __restrict__ f2p,
                                             const float* __restrict__ f1p,
                                             const float* __restrict__ w,
                                             const float* __restrict__ bmat,
                                             const float* __restrict__ v,
                                             const float* __restrict__ gamma,
                                             const float* __restrict__ beta,
                                             float* __restrict__ f2,
                                             float* __restrict__ g1p,
                                             float* __restrict__ logits,
                                             float* __restrict__ l2,
                                             float* __restrict__ out) {
    cg::grid_group grid = cg::this_grid();
    __shared__ float S[3600];
    const int blk = blockIdx.x;
    const int tid = threadIdx.x;

    // ---------------- Phase 1: f2 reduce + g1 partial GEMM ----------------
    if (blk < 512) {
        const int row = blk * 4 + (tid >> 6);   // (b*256+c)
        const int t   = tid & 63;
        if (t < 60) {
            const float* src = f2p + (size_t)row * 960 + t;
            float s = 0.f;
            #pragma unroll
            for (int k = 0; k < 16; ++k) s += src[k * 60];
            f2[(size_t)row * 60 + t] = s;
        }
    } else {
        const int blk2 = blk - 512;             // 0..479
        const int b    = blk2 / 60;
        const int rem  = blk2 % 60;
        const int tg   = rem >> 2;              // 0..14
        const int ks   = rem & 3;               // 0..3
        const int c    = tid;

        {   // stage 4 t-rows x 256-n slice (8 cg partials summed)
            const int row  = tid >> 6;          // 0..3
            const int col4 = tid & 63;          // 0..63
            const int t    = tg * 4 + row;
            vfloat4 s = (vfloat4)(0.f);
            #pragma unroll
            for (int g = 0; g < 8; ++g)
                s += *(const vfloat4*)(f1p + ((size_t)((g * 8 + b) * 60 + t)) * 1024
                                             + (ks << 8) + 4 * col4);
            *(vfloat4*)(&S[(row << 8) + 4 * col4]) = s;
        }
        __syncthreads();

        float a0 = 0.f, a1 = 0.f, a2 = 0.f, a3 = 0.f;
        const float* wp = w + (size_t)(ks << 8) * 256 + c;
        #pragma unroll 4
        for (int n = 0; n < 256; ++n) {
            const float wv = wp[n * 256];
            a0 += S[n] * wv;
            a1 += S[256 + n] * wv;
            a2 += S[512 + n] * wv;
            a3 += S[768 + n] * wv;
        }
        float* dst = g1p + ((size_t)((ks * 8 + b) * 60 + tg * 4)) * 256 + c;
        dst[0]   = a0;
        dst[256] = a1;
        dst[512] = a2;
        dst[768] = a3;
    }
    grid.sync();

    // ---------------- Phase 2: logits = sigmoid(g1·f2 + bmat) -------------
    if (blk < 480) {
        const int b  = blk / 60;
        const int t  = blk % 60;
        const int cq = tid >> 6;
        const int s  = tid & 63;

        if (tid < 64) {   // g1r: sum 4 ks partials -> S[0..256)
            vfloat4 sg = (vfloat4)(0.f);
            #pragma unroll
            for (int ks = 0; ks < 4; ++ks)
                sg += *(const vfloat4*)(g1p + ((size_t)((ks * 8 + b) * 60 + t)) * 256 + 4 * tid);
            *(vfloat4*)(&S[4 * tid]) = sg;
        }
        __syncthreads();

        float acc = 0.f;
        const float* fb = f2 + (size_t)b * 15360;
        #pragma unroll 8
        for (int cc = 0; cc < 64; ++cc) {
            const int c = cq * 64 + cc;
            acc += S[c] * fb[c * 60 + s];
        }
        S[512 + tid] = acc;                     // red -> S[512..768)
        __syncthreads();
        if (tid < 60) {
            const float x = S[512 + tid] + S[576 + tid] + S[640 + tid] + S[704 + tid]
                          + bmat[t * 60 + tid];
            logits[(size_t)blk * 60 + tid] = 1.f / (1.f + __expf(-x));
        }
    }
    grid.sync();

    // ---------------- Phase 3: l2 = v @ logits ----------------------------
    if (blk < 480) {
        const int b = blk / 60;
        const int i = blk % 60;
        const float* src = logits + (size_t)b * 3600;
        #pragma unroll
        for (int k = 0; k < 3; ++k) {
            const int idx = tid + k * 256;
            *(vfloat4*)(&S[4 * idx]) = *(const vfloat4*)(src + 4 * idx);
        }
        if (tid < 132) {
            const int idx = tid + 768;
            *(vfloat4*)(&S[4 * idx]) = *(const vfloat4*)(src + 4 * idx);
        }
        __syncthreads();

        if (tid < 60) {
            float acc = 0.f;
            #pragma unroll 4
            for (int j = 0; j < 60; ++j) acc += v[i * 60 + j] * S[j * 60 + tid];
            l2[(size_t)blk * 60 + tid] = acc;
        }
    }
    grid.sync();

    // ---------------- Phase 4: BN stats + BN + mask + softmax -------------
    if (blk < 480) {
        const int i = blk % 60;
        // ps=S[0..240), pss=S[240..480), sm=S[480..540), sr=S[540..600)
        if (tid < 240) {
            const int t = tid % 60;
            const int m = tid / 60;             // 0..3
            float s = 0.f, ss = 0.f;
            const float* src = l2 + (size_t)(m * 120) * 60 + t;
            #pragma unroll 8
            for (int k = 0; k < 120; ++k) {
                const float x = src[k * 60];
                s  += x;
                ss += x * x;
            }
            S[tid]       = s;
            S[240 + tid] = ss;
        }
        __syncthreads();
        if (tid < 60) {
            const float s   = S[tid] + S[60 + tid] + S[120 + tid] + S[180 + tid];
            const float ss  = S[240 + tid] + S[300 + tid] + S[360 + tid] + S[420 + tid];
            const float m   = s * (1.f / 480.f);
            const float var = ss * (1.f / 480.f) - m * m;
            S[480 + tid] = m;
            S[540 + tid] = rsqrtf(var + 1e-5f);
        }
        __syncthreads();

        if (tid < 64) {
            const int t = tid;
            float x = -3.0e38f;
            if (t < 60) {
                const float val = l2[(size_t)blk * 60 + t];
                const float y   = (val - S[480 + t]) * S[540 + t] * gamma[t] + beta[t];
                const int  br   = (i < 36) ? (i / 12) : 3;
                const int  lo   = (br < 3) ? br * 12 : 36;
                const int  hi   = (br < 3) ? lo + 12 : 60;
                const bool valid = (t >= lo) && (t < hi);
                x = valid ? y : (y - 1e13f);
            }
            float mx = x;
            #pragma unroll
            for (int o = 32; o > 0; o >>= 1) mx = fmaxf(mx, __shfl_xor(mx, o));
            float e = 0.f;
            if (t < 60) e = __expf(x - mx);
            float smn = e;
            #pragma unroll
            for (int o = 32; o > 0; o >>= 1) smn += __shfl_xor(smn, o);
            if (t < 60) out[(size_t)blk * 60 + t] = e / smn;
        }
    }
}

// ---------------------------------------------------------------------------
extern "C" void kernel_launch(void* const* d_in, const int* in_sizes, int n_in,
                              void* d_out, int out_size, void* d_ws, size_t ws_size,
                              hipStream_t stream) {
    const float* seq   = (const float*)d_in[0];
    const float* w1    = (const float*)d_in[1];
    const float* w2    = (const float*)d_in[2];
    const float* w     = (const float*)d_in[3];
    const float* bmat  = (const float*)d_in[4];
    const float* v     = (const float*)d_in[5];
    const float* gamma = (const float*)d_in[6];
    const float* beta  = (const float*)d_in[7];
    float* out = (float*)d_out;
    float* ws  = (float*)d_ws;

    float* f1p    = ws;                  // 3,932,160
    float* f2p    = ws + 3932160;        // 1,966,080
    float* f2     = ws + 5898240;        //   122,880
    float* g1p    = ws + 6021120;        //   491,520
    float* logits = ws + 6512640;        //    28,800
    float* l2     = ws + 6541440;        //    28,800

    kA<<<1024, 256, 0, stream>>>(seq, w1, w2, f1p, f2p);

    void* args[] = { (void*)&f2p, (void*)&f1p, (void*)&w, (void*)&bmat, (void*)&v,
                     (void*)&gamma, (void*)&beta, (void*)&f2, (void*)&g1p,
                     (void*)&logits, (void*)&l2, (void*)&out };
    hipLaunchCooperativeKernel((const void*)KT, dim3(992), dim3(256), args, 0, stream);
}

// Round 12
// 145.194 us; speedup vs baseline: 3.2381x; 3.2381x over previous
//
#include <hip/hip_runtime.h>
#include <cstdint>
#include <cstddef>

// B=8, C=256, N=1024, T=60
// seq [B][C][N][T] fp32 (503 MB), out [B][T][T] fp32
//
// R12: kA FROZEN (~89us ~roofline). K1, kG FROZEN from R10.
//  kD+kE fused into kDE (32 blocks, column-tiled): block (b,tc) computes
//  S[:, 15-col chunk] = sigmoid(g1·f2 + bmat) in LDS, then l2-chunk = v@S
//  immediately (kE's j-reduction is block-local). logits buffer eliminated.
//  4 launches (was 5).
//
// ws layout (float offsets):
//   f1p : [8 cg][B][60][1024]                 -> 3,932,160  @ 0
//   f2p : [B][C][16 chunks][60]               -> 1,966,080  @ 3,932,160
//   f2  : [B][C][60]                          ->   122,880  @ 5,898,240
//   g1p : [4 ks][B][60][C] partials over n    ->   491,520  @ 6,021,120
//   l2  : [B][60][60]                         ->    28,800  @ 6,541,440

#define CSTRIDE 61440  // 1024*60 floats per c-plane

typedef float vfloat4 __attribute__((ext_vector_type(4)));

// quad-lane (xor1 + xor2) sum via DPP quad_perm — VALU only, no LDS pipe.
__device__ __forceinline__ float quad_reduce(float x) {
    int y1 = __builtin_amdgcn_update_dpp(0, __float_as_int(x), 0xB1, 0xF, 0xF, true);
    float s1 = x + __int_as_float(y1);
    int y2 = __builtin_amdgcn_update_dpp(0, __float_as_int(s1), 0x4E, 0xF, 0xF, true);
    return s1 + __int_as_float(y2);
}

// ---------------------------------------------------------------------------
// Kernel A (FROZEN from R7; ~89us, ~roofline)
// ---------------------------------------------------------------------------
__global__ __launch_bounds__(256) void kA(const float* __restrict__ seq,
                                          const float* __restrict__ w1,
                                          const float* __restrict__ w2,
                                          float* __restrict__ f1p,
                                          float* __restrict__ f2p) {
    const int blk  = blockIdx.x;            // 1024
    const int b    = blk >> 7;              // 0..7
    const int cg_  = (blk >> 4) & 7;        // 0..7
    const int nc   = blk & 15;              // 0..15
    const int tid  = threadIdx.x;
    const int wv   = tid >> 6;              // 0..3
    const int lane = tid & 63;
    const int q    = lane & 3;              // n-sub
    const int r    = lane >> 2;             // t-quad; r==15 inactive
    const bool act = (r < 15);
    const int base_n = (nc << 6) + (wv << 4);
    const int c0   = cg_ << 5;

    __shared__ float lf2[7680];             // [cc 32][wv 4][60]

    float w2v[4];
    #pragma unroll
    for (int j = 0; j < 4; ++j) w2v[j] = w2[base_n + 4 * j + q];

    const size_t planeOff = (size_t)(b * 256 + c0) * CSTRIDE + (size_t)((base_n + q) * 60 + 4 * r);
    const float* p0 = seq + planeOff;
    const float* p1 = p0 + (size_t)CSTRIDE;
    const float* p2 = p0 + 2 * (size_t)CSTRIDE;
    const float* p3 = p0 + 3 * (size_t)CSTRIDE;

    vfloat4 P0[4], P1[4], P2[4], P3[4];
    #pragma unroll
    for (int j = 0; j < 4; ++j) {
        P0[j] = (vfloat4)(0.f);
        P1[j] = P0[j]; P2[j] = P0[j]; P3[j] = P0[j];
    }
    if (act) {
        #pragma unroll
        for (int j = 0; j < 4; ++j) P0[j] = __builtin_nontemporal_load((const vfloat4*)(p0 + j * 240));
        #pragma unroll
        for (int j = 0; j < 4; ++j) P1[j] = __builtin_nontemporal_load((const vfloat4*)(p1 + j * 240));
        #pragma unroll
        for (int j = 0; j < 4; ++j) P2[j] = __builtin_nontemporal_load((const vfloat4*)(p2 + j * 240));
        #pragma unroll
        for (int j = 0; j < 4; ++j) P3[j] = __builtin_nontemporal_load((const vfloat4*)(p3 + j * 240));
    }
    p0 += 4 * (size_t)CSTRIDE;
    p1 += 4 * (size_t)CSTRIDE;
    p2 += 4 * (size_t)CSTRIDE;
    p3 += 4 * (size_t)CSTRIDE;

    vfloat4 acc[4];
    #pragma unroll
    for (int j = 0; j < 4; ++j) acc[j] = (vfloat4)(0.f);

#define KA_STEP(P, S, PP)                                                               \
    {                                                                                   \
        const int cc = (ii << 2) + (S);                                                 \
        const float wc = w1[c0 + cc];                                                   \
        _Pragma("unroll")                                                               \
        for (int j = 0; j < 4; ++j) acc[j] += wc * P[j];                                \
        vfloat4 f2v = w2v[0]*P[0] + w2v[1]*P[1] + w2v[2]*P[2] + w2v[3]*P[3];            \
        if (pref) {                                                                     \
            _Pragma("unroll")                                                           \
            for (int j = 0; j < 4; ++j)                                                 \
                P[j] = __builtin_nontemporal_load((const vfloat4*)((PP) + j * 240));    \
        }                                                                               \
        f2v.x = quad_reduce(f2v.x);                                                     \
        f2v.y = quad_reduce(f2v.y);                                                     \
        f2v.z = quad_reduce(f2v.z);                                                     \
        f2v.w = quad_reduce(f2v.w);                                                     \
        if (act && q == 0) {                                                            \
            *(vfloat4*)(&lf2[(cc * 4 + wv) * 60 + 4 * r]) = f2v;                        \
        }                                                                               \
    }

    for (int ii = 0; ii < 8; ++ii) {
        const bool pref = act && (ii < 7);
        KA_STEP(P0, 0, p0)
        KA_STEP(P1, 1, p1)
        KA_STEP(P2, 2, p2)
        KA_STEP(P3, 3, p3)
        p0 += 4 * (size_t)CSTRIDE;
        p1 += 4 * (size_t)CSTRIDE;
        p2 += 4 * (size_t)CSTRIDE;
        p3 += 4 * (size_t)CSTRIDE;
    }
#undef KA_STEP

    if (act) {
        float* dst = f1p + ((size_t)((cg_ * 8 + b) * 60 + 4 * r)) * 1024 + base_n + q;
        #pragma unroll
        for (int j = 0; j < 4; ++j) {
            dst[0 * 1024 + 4 * j] = acc[j].x;
            dst[1 * 1024 + 4 * j] = acc[j].y;
            dst[2 * 1024 + 4 * j] = acc[j].z;
            dst[3 * 1024 + 4 * j] = acc[j].w;
        }
    }

    __syncthreads();
    #pragma unroll
    for (int k = 0; k < 2; ++k) {
        const int id4 = tid + k * 256;
        if (id4 < 480) {
            const int cc = id4 / 15;
            const int p  = id4 - cc * 15;
            vfloat4 s = (vfloat4)(0.f);
            #pragma unroll
            for (int w_ = 0; w_ < 4; ++w_)
                s += *(const vfloat4*)(&lf2[(cc * 4 + w_) * 60 + 4 * p]);
            *(vfloat4*)(f2p + ((size_t)(b * 256 + c0 + cc) * 16 + nc) * 60 + 4 * p) = s;
        }
    }
}

// ---------------------------------------------------------------------------
// K1 (FROZEN from R10): 992 blocks. [0,512): f2 reduce; [512,992): g1p GEMM.
// ---------------------------------------------------------------------------
__global__ __launch_bounds__(256) void K1(const float* __restrict__ f2p,
                                          const float* __restrict__ f1p,
                                          const float* __restrict__ w,
                                          float* __restrict__ f2,
                                          float* __restrict__ g1p) {
    const int blk = blockIdx.x;
    const int tid = threadIdx.x;
    if (blk < 512) {
        const int row = blk * 4 + (tid >> 6);   // (b*256+c)
        const int t   = tid & 63;
        if (t >= 60) return;
        const float* src = f2p + (size_t)row * 960 + t;
        float s = 0.f;
        #pragma unroll
        for (int k = 0; k < 16; ++k) s += src[k * 60];
        f2[(size_t)row * 60 + t] = s;
    } else {
        const int blk2 = blk - 512;             // 0..479
        const int b    = blk2 / 60;
        const int rem  = blk2 % 60;
        const int tg   = rem >> 2;              // 0..14
        const int ks   = rem & 3;               // 0..3
        const int c    = tid;

        __shared__ float fl[1024];              // 4 rows x 256-n slice

        {
            const int row  = tid >> 6;          // 0..3
            const int col4 = tid & 63;          // 0..63
            const int t    = tg * 4 + row;
            vfloat4 s = (vfloat4)(0.f);
            #pragma unroll
            for (int g = 0; g < 8; ++g)
                s += *(const vfloat4*)(f1p + ((size_t)((g * 8 + b) * 60 + t)) * 1024
                                             + (ks << 8) + 4 * col4);
            *(vfloat4*)(&fl[(row << 8) + 4 * col4]) = s;
        }
        __syncthreads();

        float a0 = 0.f, a1 = 0.f, a2 = 0.f, a3 = 0.f;
        const float* wp = w + (size_t)(ks << 8) * 256 + c;
        #pragma unroll 4
        for (int n = 0; n < 256; ++n) {
            const float wv = wp[n * 256];
            a0 += fl[n] * wv;
            a1 += fl[256 + n] * wv;
            a2 += fl[512 + n] * wv;
            a3 += fl[768 + n] * wv;
        }
        float* dst = g1p + ((size_t)((ks * 8 + b) * 60 + tg * 4)) * 256 + c;
        dst[0]   = a0;
        dst[256] = a1;
        dst[512] = a2;
        dst[768] = a3;
    }
}

// ---------------------------------------------------------------------------
// kDE: fused logits+PV, column-tiled. grid 32 = b(8) x tc(4), block 256.
//  F[t'][c]  : f2[b][:, 15-col chunk], transposed for b128 c-reads.
//  Loop 4 j-groups: Gr[16][c] = ks-reduced g1p rows; 240 threads (jl,t')
//    compute S[jb*16+jl][t'] = sigmoid(Gr[jl]·F[t'] + bmat).
//  Then l2[b,i,chunk] = v @ S  (kE's j-reduction is block-local).
// ---------------------------------------------------------------------------
__global__ __launch_bounds__(256) void kDE(const float* __restrict__ g1p,
                                           const float* __restrict__ f2,
                                           const float* __restrict__ bmat,
                                           const float* __restrict__ v,
                                           float* __restrict__ l2) {
    const int blk   = blockIdx.x;        // 32
    const int b     = blk >> 2;
    const int tc    = blk & 3;
    const int tbase = tc * 15;
    const int tid   = threadIdx.x;

    __shared__ float F[15][260];         // [t'][c], pitch 260 (16B-aligned rows)
    __shared__ float Gr[16][264];        // [j_local][c], pitch 264
    __shared__ float S[60][16];          // [j][t']

    // stage F (transpose): 3840 elements, 15 per thread
    #pragma unroll
    for (int k = 0; k < 15; ++k) {
        const int idx = tid + k * 256;   // 0..3839
        const int c   = idx / 15;
        const int tp  = idx % 15;
        F[tp][c] = f2[(size_t)b * 15360 + c * 60 + tbase + tp];
    }
    __syncthreads();

    const int jl = tid / 15;             // 0..16 (active <240 -> 0..15)
    const int tp = tid % 15;

    for (int jb = 0; jb < 4; ++jb) {
        // stage Gr: 16 j-rows, ks-reduced. 1024 float4 slots, 4 per thread.
        #pragma unroll
        for (int k = 0; k < 4; ++k) {
            const int idx = tid + k * 256;      // 0..1023
            const int j   = idx >> 6;           // 0..15
            const int c4  = idx & 63;
            vfloat4 s = (vfloat4)(0.f);
            #pragma unroll
            for (int ks = 0; ks < 4; ++ks)
                s += *(const vfloat4*)(g1p + ((size_t)((ks * 8 + b) * 60 + jb * 16 + j)) * 256 + 4 * c4);
            *(vfloat4*)(&Gr[j][4 * c4]) = s;
        }
        __syncthreads();

        if (tid < 240) {
            float acc = 0.f;
            #pragma unroll 8
            for (int c4 = 0; c4 < 64; ++c4) {
                const vfloat4 g = *(const vfloat4*)(&Gr[jl][4 * c4]);
                const vfloat4 f = *(const vfloat4*)(&F[tp][4 * c4]);
                acc += g.x * f.x + g.y * f.y + g.z * f.z + g.w * f.w;
            }
            const int j = jb * 16 + jl;
            const float x = acc + bmat[j * 60 + tbase + tp];
            S[j][tp] = 1.f / (1.f + __expf(-x));
        }
        __syncthreads();
    }

    // PV: l2[b, i, tbase+t2] = sum_j v[i,j] * S[j][t2]. 900 outputs.
    if (tid < 240) {
        #pragma unroll
        for (int k = 0; k < 4; ++k) {
            const int idx = tid + k * 240;
            if (idx < 900) {
                const int i  = idx / 15;
                const int t2 = idx % 15;
                float acc = 0.f;
                #pragma unroll 4
                for (int j = 0; j < 60; ++j) acc += v[i * 60 + j] * S[j][t2];
                l2[((size_t)b * 60 + i) * 60 + tbase + t2] = acc;
            }
        }
    }
}

// ---------------------------------------------------------------------------
// Kernel G (FROZEN from R10): per-block BN stats + BN + mask + softmax.
// ---------------------------------------------------------------------------
__global__ __launch_bounds__(256) void kG(const float* __restrict__ l2,
                                          const float* __restrict__ gamma,
                                          const float* __restrict__ beta,
                                          float* __restrict__ out) {
    const int bi = blockIdx.x;
    const int i  = bi % 60;
    const int tid = threadIdx.x;

    __shared__ float ps[240];
    __shared__ float pss[240];
    __shared__ float sm[60];
    __shared__ float sr[60];

    if (tid < 240) {
        const int t = tid % 60;
        const int m = tid / 60;                // 0..3
        float s = 0.f, ss = 0.f;
        const float* src = l2 + (size_t)(m * 120) * 60 + t;
        #pragma unroll 8
        for (int k = 0; k < 120; ++k) {
            const float x = src[k * 60];
            s  += x;
            ss += x * x;
        }
        ps[tid]  = s;
        pss[tid] = ss;
    }
    __syncthreads();
    if (tid < 60) {
        const float s   = ps[tid] + ps[60 + tid] + ps[120 + tid] + ps[180 + tid];
        const float ss  = pss[tid] + pss[60 + tid] + pss[120 + tid] + pss[180 + tid];
        const float m   = s * (1.f / 480.f);
        const float var = ss * (1.f / 480.f) - m * m;
        sm[tid] = m;
        sr[tid] = rsqrtf(var + 1e-5f);
    }
    __syncthreads();

    if (tid < 64) {
        const int t = tid;
        float x = -3.0e38f;
        if (t < 60) {
            const float val = l2[(size_t)bi * 60 + t];
            const float y   = (val - sm[t]) * sr[t] * gamma[t] + beta[t];
            const int  br   = (i < 36) ? (i / 12) : 3;
            const int  lo   = (br < 3) ? br * 12 : 36;
            const int  hi   = (br < 3) ? lo + 12 : 60;
            const bool valid = (t >= lo) && (t < hi);
            x = valid ? y : (y - 1e13f);
        }
        float mx = x;
        #pragma unroll
        for (int o = 32; o > 0; o >>= 1) mx = fmaxf(mx, __shfl_xor(mx, o));
        float e = 0.f;
        if (t < 60) e = __expf(x - mx);
        float smn = e;
        #pragma unroll
        for (int o = 32; o > 0; o >>= 1) smn += __shfl_xor(smn, o);
        if (t < 60) out[(size_t)bi * 60 + t] = e / smn;
    }
}

// ---------------------------------------------------------------------------
extern "C" void kernel_launch(void* const* d_in, const int* in_sizes, int n_in,
                              void* d_out, int out_size, void* d_ws, size_t ws_size,
                              hipStream_t stream) {
    const float* seq   = (const float*)d_in[0];
    const float* w1    = (const float*)d_in[1];
    const float* w2    = (const float*)d_in[2];
    const float* w     = (const float*)d_in[3];
    const float* bmat  = (const float*)d_in[4];
    const float* v     = (const float*)d_in[5];
    const float* gamma = (const float*)d_in[6];
    const float* beta  = (const float*)d_in[7];
    float* out = (float*)d_out;
    float* ws  = (float*)d_ws;

    float* f1p = ws;                  // 3,932,160
    float* f2p = ws + 3932160;        // 1,966,080
    float* f2  = ws + 5898240;        //   122,880
    float* g1p = ws + 6021120;        //   491,520
    float* l2  = ws + 6541440;        //    28,800

    kA<<<1024, 256, 0, stream>>>(seq, w1, w2, f1p, f2p);
    K1<<<992, 256, 0, stream>>>(f2p, f1p, w, f2, g1p);
    kDE<<<32, 256, 0, stream>>>(g1p, f2, bmat, v, l2);
    kG<<<480, 256, 0, stream>>>(l2, gamma, beta, out);
}

// Round 13
// 131.739 us; speedup vs baseline: 3.5688x; 1.1021x over previous
//
#include <hip/hip_runtime.h>
#include <cstdint>
#include <cstddef>

// B=8, C=256, N=1024, T=60
// seq [B][C][N][T] fp32 (503 MB), out [B][T][T] fp32
//
// R13 = revert to R10 (best measured: 131.8us; R12 fusion regressed to 145).
// kA FROZEN (~89us, probe-verified ~roofline). 5 launches.
//
// ws layout (float offsets):
//   f1p : [8 cg][B][60][1024]                 -> 3,932,160  @ 0
//   f2p : [B][C][16 chunks][60]               -> 1,966,080  @ 3,932,160
//   f2  : [B][C][60]                          ->   122,880  @ 5,898,240
//   g1p : [4 ks][B][60][C] partials over n    ->   491,520  @ 6,021,120
//   logits: [B][60][60]                       ->    28,800  @ 6,512,640
//   l2  : [B][60][60]                         ->    28,800  @ 6,541,440

#define CSTRIDE 61440  // 1024*60 floats per c-plane

typedef float vfloat4 __attribute__((ext_vector_type(4)));

// quad-lane (xor1 + xor2) sum via DPP quad_perm — VALU only, no LDS pipe.
__device__ __forceinline__ float quad_reduce(float x) {
    int y1 = __builtin_amdgcn_update_dpp(0, __float_as_int(x), 0xB1, 0xF, 0xF, true);
    float s1 = x + __int_as_float(y1);
    int y2 = __builtin_amdgcn_update_dpp(0, __float_as_int(s1), 0x4E, 0xF, 0xF, true);
    return s1 + __int_as_float(y2);
}

// ---------------------------------------------------------------------------
// Kernel A (FROZEN from R7; ~89us, ~roofline): 4-deep NT pipeline; DPP f2
// reduce; LDS buffer; cross-wave reduce + flush to f2p [B][C][16][60].
// ---------------------------------------------------------------------------
__global__ __launch_bounds__(256) void kA(const float* __restrict__ seq,
                                          const float* __restrict__ w1,
                                          const float* __restrict__ w2,
                                          float* __restrict__ f1p,
                                          float* __restrict__ f2p) {
    const int blk  = blockIdx.x;            // 1024
    const int b    = blk >> 7;              // 0..7
    const int cg_  = (blk >> 4) & 7;        // 0..7
    const int nc   = blk & 15;              // 0..15
    const int tid  = threadIdx.x;
    const int wv   = tid >> 6;              // 0..3
    const int lane = tid & 63;
    const int q    = lane & 3;              // n-sub
    const int r    = lane >> 2;             // t-quad; r==15 inactive
    const bool act = (r < 15);
    const int base_n = (nc << 6) + (wv << 4);
    const int c0   = cg_ << 5;

    __shared__ float lf2[7680];             // [cc 32][wv 4][60]

    float w2v[4];
    #pragma unroll
    for (int j = 0; j < 4; ++j) w2v[j] = w2[base_n + 4 * j + q];

    const size_t planeOff = (size_t)(b * 256 + c0) * CSTRIDE + (size_t)((base_n + q) * 60 + 4 * r);
    const float* p0 = seq + planeOff;
    const float* p1 = p0 + (size_t)CSTRIDE;
    const float* p2 = p0 + 2 * (size_t)CSTRIDE;
    const float* p3 = p0 + 3 * (size_t)CSTRIDE;

    vfloat4 P0[4], P1[4], P2[4], P3[4];
    #pragma unroll
    for (int j = 0; j < 4; ++j) {
        P0[j] = (vfloat4)(0.f);
        P1[j] = P0[j]; P2[j] = P0[j]; P3[j] = P0[j];
    }
    if (act) {
        #pragma unroll
        for (int j = 0; j < 4; ++j) P0[j] = __builtin_nontemporal_load((const vfloat4*)(p0 + j * 240));
        #pragma unroll
        for (int j = 0; j < 4; ++j) P1[j] = __builtin_nontemporal_load((const vfloat4*)(p1 + j * 240));
        #pragma unroll
        for (int j = 0; j < 4; ++j) P2[j] = __builtin_nontemporal_load((const vfloat4*)(p2 + j * 240));
        #pragma unroll
        for (int j = 0; j < 4; ++j) P3[j] = __builtin_nontemporal_load((const vfloat4*)(p3 + j * 240));
    }
    p0 += 4 * (size_t)CSTRIDE;
    p1 += 4 * (size_t)CSTRIDE;
    p2 += 4 * (size_t)CSTRIDE;
    p3 += 4 * (size_t)CSTRIDE;

    vfloat4 acc[4];
    #pragma unroll
    for (int j = 0; j < 4; ++j) acc[j] = (vfloat4)(0.f);

#define KA_STEP(P, S, PP)                                                               \
    {                                                                                   \
        const int cc = (ii << 2) + (S);                                                 \
        const float wc = w1[c0 + cc];                                                   \
        _Pragma("unroll")                                                               \
        for (int j = 0; j < 4; ++j) acc[j] += wc * P[j];                                \
        vfloat4 f2v = w2v[0]*P[0] + w2v[1]*P[1] + w2v[2]*P[2] + w2v[3]*P[3];            \
        if (pref) {                                                                     \
            _Pragma("unroll")                                                           \
            for (int j = 0; j < 4; ++j)                                                 \
                P[j] = __builtin_nontemporal_load((const vfloat4*)((PP) + j * 240));    \
        }                                                                               \
        f2v.x = quad_reduce(f2v.x);                                                     \
        f2v.y = quad_reduce(f2v.y);                                                     \
        f2v.z = quad_reduce(f2v.z);                                                     \
        f2v.w = quad_reduce(f2v.w);                                                     \
        if (act && q == 0) {                                                            \
            *(vfloat4*)(&lf2[(cc * 4 + wv) * 60 + 4 * r]) = f2v;                        \
        }                                                                               \
    }

    for (int ii = 0; ii < 8; ++ii) {
        const bool pref = act && (ii < 7);
        KA_STEP(P0, 0, p0)
        KA_STEP(P1, 1, p1)
        KA_STEP(P2, 2, p2)
        KA_STEP(P3, 3, p3)
        p0 += 4 * (size_t)CSTRIDE;
        p1 += 4 * (size_t)CSTRIDE;
        p2 += 4 * (size_t)CSTRIDE;
        p3 += 4 * (size_t)CSTRIDE;
    }
#undef KA_STEP

    if (act) {
        float* dst = f1p + ((size_t)((cg_ * 8 + b) * 60 + 4 * r)) * 1024 + base_n + q;
        #pragma unroll
        for (int j = 0; j < 4; ++j) {
            dst[0 * 1024 + 4 * j] = acc[j].x;
            dst[1 * 1024 + 4 * j] = acc[j].y;
            dst[2 * 1024 + 4 * j] = acc[j].z;
            dst[3 * 1024 + 4 * j] = acc[j].w;
        }
    }

    __syncthreads();
    #pragma unroll
    for (int k = 0; k < 2; ++k) {
        const int id4 = tid + k * 256;
        if (id4 < 480) {
            const int cc = id4 / 15;
            const int p  = id4 - cc * 15;
            vfloat4 s = (vfloat4)(0.f);
            #pragma unroll
            for (int w_ = 0; w_ < 4; ++w_)
                s += *(const vfloat4*)(&lf2[(cc * 4 + w_) * 60 + 4 * p]);
            *(vfloat4*)(f2p + ((size_t)(b * 256 + c0 + cc) * 16 + nc) * 60 + 4 * p) = s;
        }
    }
}

// ---------------------------------------------------------------------------
// K1 (FROZEN from R10): 992 blocks. [0,512): f2 reduce; [512,992): g1p GEMM.
// ---------------------------------------------------------------------------
__global__ __launch_bounds__(256) void K1(const float* __restrict__ f2p,
                                          const float* __restrict__ f1p,
                                          const float* __restrict__ w,
                                          float* __restrict__ f2,
                                          float* __restrict__ g1p) {
    const int blk = blockIdx.x;
    const int tid = threadIdx.x;
    if (blk < 512) {
        const int row = blk * 4 + (tid >> 6);   // (b*256+c)
        const int t   = tid & 63;
        if (t >= 60) return;
        const float* src = f2p + (size_t)row * 960 + t;
        float s = 0.f;
        #pragma unroll
        for (int k = 0; k < 16; ++k) s += src[k * 60];
        f2[(size_t)row * 60 + t] = s;
    } else {
        const int blk2 = blk - 512;             // 0..479
        const int b    = blk2 / 60;
        const int rem  = blk2 % 60;
        const int tg   = rem >> 2;              // 0..14
        const int ks   = rem & 3;               // 0..3
        const int c    = tid;

        __shared__ float fl[1024];              // 4 rows x 256-n slice

        {
            const int row  = tid >> 6;          // 0..3
            const int col4 = tid & 63;          // 0..63
            const int t    = tg * 4 + row;
            vfloat4 s = (vfloat4)(0.f);
            #pragma unroll
            for (int g = 0; g < 8; ++g)
                s += *(const vfloat4*)(f1p + ((size_t)((g * 8 + b) * 60 + t)) * 1024
                                             + (ks << 8) + 4 * col4);
            *(vfloat4*)(&fl[(row << 8) + 4 * col4]) = s;
        }
        __syncthreads();

        float a0 = 0.f, a1 = 0.f, a2 = 0.f, a3 = 0.f;
        const float* wp = w + (size_t)(ks << 8) * 256 + c;
        #pragma unroll 4
        for (int n = 0; n < 256; ++n) {
            const float wv = wp[n * 256];
            a0 += fl[n] * wv;
            a1 += fl[256 + n] * wv;
            a2 += fl[512 + n] * wv;
            a3 += fl[768 + n] * wv;
        }
        float* dst = g1p + ((size_t)((ks * 8 + b) * 60 + tg * 4)) * 256 + c;
        dst[0]   = a0;
        dst[256] = a1;
        dst[512] = a2;
        dst[768] = a3;
    }
}

// ---------------------------------------------------------------------------
// Kernel D (FROZEN from R9): absorbs g1 4-partial reduction during staging.
// ---------------------------------------------------------------------------
__global__ __launch_bounds__(256) void kD(const float* __restrict__ g1p,
                                          const float* __restrict__ f2,
                                          const float* __restrict__ bmat,
                                          float* __restrict__ logits) {
    const int bt = blockIdx.x;
    const int b  = bt / 60;
    const int t  = bt % 60;
    const int tid = threadIdx.x;
    const int cq = tid >> 6;
    const int s  = tid & 63;

    __shared__ float f2s[15364];
    __shared__ float g1r[256];
    __shared__ float red[256];

    const float* fsrc = f2 + (size_t)b * 15360;
    #pragma unroll
    for (int k = 0; k < 15; ++k) {
        const int idx = tid + k * 256;
        *(float4*)(&f2s[4 * idx]) = *(const float4*)(fsrc + 4 * idx);
    }
    if (tid < 64) {
        vfloat4 sg = (vfloat4)(0.f);
        #pragma unroll
        for (int ks = 0; ks < 4; ++ks)
            sg += *(const vfloat4*)(g1p + ((size_t)((ks * 8 + b) * 60 + t)) * 256 + 4 * tid);
        *(vfloat4*)(&g1r[4 * tid]) = sg;
    }
    __syncthreads();

    float acc = 0.f;
    #pragma unroll 8
    for (int cc = 0; cc < 64; ++cc) {
        const int c = cq * 64 + cc;
        acc += g1r[c] * f2s[c * 60 + s];
    }
    red[tid] = acc;
    __syncthreads();
    if (tid < 60) {
        const float x = red[tid] + red[64 + tid] + red[128 + tid] + red[192 + tid]
                      + bmat[t * 60 + tid];
        logits[(size_t)bt * 60 + tid] = 1.f / (1.f + __expf(-x));
    }
}

// ---------------------------------------------------------------------------
// Kernel E (FROZEN from R3)
// ---------------------------------------------------------------------------
__global__ __launch_bounds__(256) void kE(const float* __restrict__ v,
                                          const float* __restrict__ logits,
                                          float* __restrict__ l2) {
    const int bi = blockIdx.x;
    const int b  = bi / 60;
    const int i  = bi % 60;
    const int tid = threadIdx.x;

    __shared__ float L[3600];
    const float* src = logits + (size_t)b * 3600;
    #pragma unroll
    for (int k = 0; k < 3; ++k) {
        const int idx = tid + k * 256;
        *(float4*)(&L[4 * idx]) = *(const float4*)(src + 4 * idx);
    }
    if (tid < 132) {
        const int idx = tid + 768;
        *(float4*)(&L[4 * idx]) = *(const float4*)(src + 4 * idx);
    }
    __syncthreads();

    if (tid < 60) {
        float acc = 0.f;
        #pragma unroll 4
        for (int j = 0; j < 60; ++j) acc += v[i * 60 + j] * L[j * 60 + tid];
        l2[(size_t)bi * 60 + tid] = acc;
    }
}

// ---------------------------------------------------------------------------
// Kernel G (FROZEN from R10): per-block BN stats + BN + mask + softmax.
// ---------------------------------------------------------------------------
__global__ __launch_bounds__(256) void kG(const float* __restrict__ l2,
                                          const float* __restrict__ gamma,
                                          const float* __restrict__ beta,
                                          float* __restrict__ out) {
    const int bi = blockIdx.x;
    const int i  = bi % 60;
    const int tid = threadIdx.x;

    __shared__ float ps[240];
    __shared__ float pss[240];
    __shared__ float sm[60];
    __shared__ float sr[60];

    if (tid < 240) {
        const int t = tid % 60;
        const int m = tid / 60;                // 0..3
        float s = 0.f, ss = 0.f;
        const float* src = l2 + (size_t)(m * 120) * 60 + t;
        #pragma unroll 8
        for (int k = 0; k < 120; ++k) {
            const float x = src[k * 60];
            s  += x;
            ss += x * x;
        }
        ps[tid]  = s;
        pss[tid] = ss;
    }
    __syncthreads();
    if (tid < 60) {
        const float s   = ps[tid] + ps[60 + tid] + ps[120 + tid] + ps[180 + tid];
        const float ss  = pss[tid] + pss[60 + tid] + pss[120 + tid] + pss[180 + tid];
        const float m   = s * (1.f / 480.f);
        const float var = ss * (1.f / 480.f) - m * m;
        sm[tid] = m;
        sr[tid] = rsqrtf(var + 1e-5f);
    }
    __syncthreads();

    if (tid < 64) {
        const int t = tid;
        float x = -3.0e38f;
        if (t < 60) {
            const float val = l2[(size_t)bi * 60 + t];
            const float y   = (val - sm[t]) * sr[t] * gamma[t] + beta[t];
            const int  br   = (i < 36) ? (i / 12) : 3;
            const int  lo   = (br < 3) ? br * 12 : 36;
            const int  hi   = (br < 3) ? lo + 12 : 60;
            const bool valid = (t >= lo) && (t < hi);
            x = valid ? y : (y - 1e13f);
        }
        float mx = x;
        #pragma unroll
        for (int o = 32; o > 0; o >>= 1) mx = fmaxf(mx, __shfl_xor(mx, o));
        float e = 0.f;
        if (t < 60) e = __expf(x - mx);
        float smn = e;
        #pragma unroll
        for (int o = 32; o > 0; o >>= 1) smn += __shfl_xor(smn, o);
        if (t < 60) out[(size_t)bi * 60 + t] = e / smn;
    }
}

// ---------------------------------------------------------------------------
extern "C" void kernel_launch(void* const* d_in, const int* in_sizes, int n_in,
                              void* d_out, int out_size, void* d_ws, size_t ws_size,
                              hipStream_t stream) {
    const float* seq   = (const float*)d_in[0];
    const float* w1    = (const float*)d_in[1];
    const float* w2    = (const float*)d_in[2];
    const float* w     = (const float*)d_in[3];
    const float* bmat  = (const float*)d_in[4];
    const float* v     = (const float*)d_in[5];
    const float* gamma = (const float*)d_in[6];
    const float* beta  = (const float*)d_in[7];
    float* out = (float*)d_out;
    float* ws  = (float*)d_ws;

    float* f1p    = ws;                  // 3,932,160
    float* f2p    = ws + 3932160;        // 1,966,080
    float* f2     = ws + 5898240;        //   122,880
    float* g1p    = ws + 6021120;        //   491,520
    float* logits = ws + 6512640;        //    28,800
    float* l2     = ws + 6541440;        //    28,800

    kA<<<1024, 256, 0, stream>>>(seq, w1, w2, f1p, f2p);
    K1<<<992, 256, 0, stream>>>(f2p, f1p, w, f2, g1p);
    kD<<<480, 256, 0, stream>>>(g1p, f2, bmat, logits);
    kE<<<480, 256, 0, stream>>>(v, logits, l2);
    kG<<<480, 256, 0, stream>>>(l2, gamma, beta, out);
}